// Round 1
// baseline (101.433 us; speedup 1.0000x reference)
//
#include <hip/hip_runtime.h>

// SwitchLinear: out[b] = x[b] @ (W[route[b]] + Wf)^T + bias[route[b]] + bf
// B=4096, IN=OUT=256, E=16.
//
// SINGLE-dispatch, workspace-free version:
//  - Each block (e, j) owns sorted-slot window [16j, 16j+16) of expert e.
//  - Block preamble computes the per-source-block histogram of expert e
//    directly from ridx (16 KB read, L2-hot) -> no part[] buffer, no
//    histogram kernel.
//  - B-operand is loaded as fp32 W[e] + Wf and converted to bf16 in-register
//    inside the MFMA loop -> no wsum buffer, no prep kernel, no workspace.
//  - Grid is expert-major (e = blockIdx.x) so expert e's blocks land on
//    XCD e&7: each XCD L2 caches only 2 experts' weights.

#define B_TOK 4096
#define IN_F 256
#define OUT_F 256
#define NEXP 16
#define WEL (OUT_F * IN_F)  // 65536 elems per expert weight
#define NSB 16              // source blocks of 256 tokens each

typedef __attribute__((ext_vector_type(8))) short bhalf8;  // 8 bf16 = 4 VGPRs
typedef __attribute__((ext_vector_type(4))) float v4f;     // MFMA accumulator

__device__ __forceinline__ unsigned short f2bf(float f) {
    unsigned u = __float_as_uint(f);
    u += 0x7FFFu + ((u >> 16) & 1u);  // round-nearest-even
    return (unsigned short)(u >> 16);
}

__device__ __forceinline__ bhalf8 cvt8(float4 a0, float4 a1) {
    bhalf8 v;
    v[0] = (short)f2bf(a0.x); v[1] = (short)f2bf(a0.y);
    v[2] = (short)f2bf(a0.z); v[3] = (short)f2bf(a0.w);
    v[4] = (short)f2bf(a1.x); v[5] = (short)f2bf(a1.y);
    v[6] = (short)f2bf(a1.z); v[7] = (short)f2bf(a1.w);
    return v;
}

__global__ __launch_bounds__(256) void k_fused(
    const float* __restrict__ x, const int* __restrict__ ridx,
    const float* __restrict__ w, const float* __restrict__ wf,
    const float* __restrict__ bias, const float* __restrict__ bfv,
    float* __restrict__ out) {
    __shared__ int pfx[NSB + 1];
    __shared__ int pcs[NSB];
    __shared__ int wc[4];
    __shared__ int stk[16];

    int e = blockIdx.x;  // expert-major: consecutive blocks -> different XCDs
    int j = blockIdx.y;
    int tid = threadIdx.x;
    int wave = tid >> 6;
    int lane = tid & 63;

    // ---- per-block histogram: pcs[sb] = #tokens of expert e in source
    // block sb. Thread tid covers tokens [16*tid, 16*tid+16), all inside
    // sb = tid >> 4; 16-lane shuffle reduce then serial prefix. ----
    {
        int c = 0;
        const int4* rp = (const int4*)(ridx + tid * 16);
        #pragma unroll
        for (int i = 0; i < 4; ++i) {
            int4 v = rp[i];
            c += (v.x == e) + (v.y == e) + (v.z == e) + (v.w == e);
        }
        #pragma unroll
        for (int s = 1; s < 16; s <<= 1) c += __shfl_xor(c, s);
        if ((tid & 15) == 0) pcs[tid >> 4] = c;
    }
    __syncthreads();
    if (tid == 0) {
        int a = 0;
        for (int sb = 0; sb < NSB; ++sb) { pfx[sb] = a; a += pcs[sb]; }
        pfx[NSB] = a;
    }
    __syncthreads();

    int cnt = pfx[NSB];
    int start = j * 16;
    if (start >= cnt) return;  // block-uniform
    int rem = cnt - start;
    int rows = rem < 16 ? rem : 16;
    int end = start + rows;

    // ---- token-id reconstruction: ballot + prefix rank over the 1-2
    // source blocks covering the window (verbatim from verified kernel). ----
    for (int sb = 0; sb < NSB; ++sb) {
        if (pfx[sb + 1] <= start || pfx[sb] >= end) continue;  // block-uniform
        int tok = sb * 256 + tid;
        bool m = (ridx[tok] == e);
        unsigned long long mask = __ballot(m);
        if (lane == 0) wc[wave] = (int)__popcll(mask);
        __syncthreads();
        int wbase = 0;
        for (int wv = 0; wv < wave; ++wv) wbase += wc[wv];
        int rank = wbase + (int)__popcll(mask & ((1ull << lane) - 1ull));
        int slot = pfx[sb] + rank;
        if (m && slot >= start && slot < end) stk[slot - start] = tok;
        __syncthreads();
    }
    if (tid < 16 && tid >= rows) stk[tid] = stk[0];  // pad with a valid token
    __syncthreads();

    int l15 = lane & 15;
    int quad = lane >> 4;

    // ---- 16x256 (K=256) MFMA tile. A from fp32 x, B from fp32 W[e]+Wf,
    // both converted to bf16 in-register. Each fp32 weight element of
    // expert e is loaded exactly once per block. ----
    const float* xrow = x + stk[l15] * IN_F + quad * 8;
    const float* wrow = w + e * WEL + (wave * 64 + l15) * IN_F + quad * 8;
    const float* frow = wf + (wave * 64 + l15) * IN_F + quad * 8;

    v4f acc[4];
    #pragma unroll
    for (int n = 0; n < 4; ++n) acc[n] = (v4f){0.f, 0.f, 0.f, 0.f};

    #pragma unroll
    for (int ks = 0; ks < 8; ++ks) {
        const float4 a0 = *(const float4*)(xrow + ks * 32);
        const float4 a1 = *(const float4*)(xrow + ks * 32 + 4);
        bhalf8 a = cvt8(a0, a1);
        #pragma unroll
        for (int n = 0; n < 4; ++n) {
            const float* wp = wrow + n * (16 * IN_F) + ks * 32;
            const float* fp = frow + n * (16 * IN_F) + ks * 32;
            const float4 b0 = *(const float4*)(wp);
            const float4 b1 = *(const float4*)(wp + 4);
            const float4 g0 = *(const float4*)(fp);
            const float4 g1 = *(const float4*)(fp + 4);
            float4 s0 = make_float4(b0.x + g0.x, b0.y + g0.y,
                                    b0.z + g0.z, b0.w + g0.w);
            float4 s1 = make_float4(b1.x + g1.x, b1.y + g1.y,
                                    b1.z + g1.z, b1.w + g1.w);
            bhalf8 b = cvt8(s0, s1);
            acc[n] = __builtin_amdgcn_mfma_f32_16x16x32_bf16(a, b, acc[n], 0, 0, 0);
        }
    }

    // ---- epilogue: bias + bias_fact, scatter rows to out (verbatim). ----
    #pragma unroll
    for (int n = 0; n < 4; ++n) {
        int m = wave * 64 + n * 16 + l15;
        float bb = bias[e * OUT_F + m] + bfv[m];
        #pragma unroll
        for (int r = 0; r < 4; ++r) {
            int row = quad * 4 + r;
            if (row < rows) out[stk[row] * OUT_F + m] = acc[n][r] + bb;
        }
    }
}

extern "C" void kernel_launch(void* const* d_in, const int* in_sizes, int n_in,
                              void* d_out, int out_size, void* d_ws, size_t ws_size,
                              hipStream_t stream) {
    (void)in_sizes; (void)n_in; (void)out_size; (void)d_ws; (void)ws_size;
    const float* x = (const float*)d_in[0];
    const int* ridx = (const int*)d_in[1];
    const float* w = (const float*)d_in[2];
    const float* wf = (const float*)d_in[3];
    const float* bias = (const float*)d_in[4];
    const float* bf = (const float*)d_in[5];
    float* out = (float*)d_out;

    // capacity 32 tiles/expert = 512 tokens; counts are Binomial(4096, 1/16)
    // (mean 256, sigma 15.5) -> 16.5 sigma margin.
    k_fused<<<dim3(NEXP, 32), 256, 0, stream>>>(x, ridx, w, wf, bias, bf, out);
}

// Round 2
// 88.899 us; speedup vs baseline: 1.1410x; 1.1410x over previous
//
#include <hip/hip_runtime.h>

// SwitchLinear: out[b] = x[b] @ (W[route[b]] + Wf)^T + bias[route[b]] + bf
// B=4096, IN=OUT=256, E=16.
//
// 2-dispatch pipeline (round-0 structure, fatter GEMM blocks):
//  1. k_conv: wsum = bf16(W[e]+Wf) for all experts (512 blocks, streaming).
//  2. k_gemm: grid (e=16, j=8); block (e,j) owns sorted-slot window
//     [64j, 64j+64) of expert e. Preamble computes the per-source-block
//     histogram of expert e directly from ridx (16 KB L2-hot read + shuffle
//     reduce -> no part[] buffer), reconstructs its 64 token ids via
//     ballot/prefix rank, then computes a 64x256 (K=256) tile as 4 token
//     sub-tiles sharing each B fragment: wsum is read ONCE per block
//     (16 MB aggregate vs 64 MB in the 16-token version). A is loaded fp32
//     and converted in-register; bias folded in the epilogue.

#define B_TOK 4096
#define IN_F 256
#define OUT_F 256
#define NEXP 16
#define WEL (OUT_F * IN_F)  // 65536 elems per expert weight
#define NSB 16              // source blocks of 256 tokens each
#define TPB 64              // tokens per gemm block
#define JTILES 8            // TPB*JTILES = 512 capacity/expert (16.5 sigma)

typedef __attribute__((ext_vector_type(8))) short bhalf8;  // 8 bf16 = 4 VGPRs
typedef __attribute__((ext_vector_type(4))) float v4f;     // MFMA accumulator

#define WSUM_OFF 0u  // ushort[1048576] bf16(W[e]+Wf) in workspace

__device__ __forceinline__ unsigned short f2bf(float f) {
    unsigned u = __float_as_uint(f);
    u += 0x7FFFu + ((u >> 16) & 1u);  // round-nearest-even
    return (unsigned short)(u >> 16);
}

__device__ __forceinline__ bhalf8 cvt8(float4 a0, float4 a1) {
    bhalf8 v;
    v[0] = (short)f2bf(a0.x); v[1] = (short)f2bf(a0.y);
    v[2] = (short)f2bf(a0.z); v[3] = (short)f2bf(a0.w);
    v[4] = (short)f2bf(a1.x); v[5] = (short)f2bf(a1.y);
    v[6] = (short)f2bf(a1.z); v[7] = (short)f2bf(a1.w);
    return v;
}

// 512 blocks: wsum = bf16(W + Wf), 8 elems/thread, streaming.
__global__ __launch_bounds__(256) void k_conv(
    const float* __restrict__ w, const float* __restrict__ wf,
    unsigned short* __restrict__ wsum) {
    int id = (blockIdx.x * 256 + threadIdx.x) * 8;
    const float4 a0 = *(const float4*)(w + id);
    const float4 a1 = *(const float4*)(w + id + 4);
    int fo = id & (WEL - 1);
    const float4 f0 = *(const float4*)(wf + fo);
    const float4 f1 = *(const float4*)(wf + fo + 4);
    float4 s0 = make_float4(a0.x + f0.x, a0.y + f0.y, a0.z + f0.z, a0.w + f0.w);
    float4 s1 = make_float4(a1.x + f1.x, a1.y + f1.y, a1.z + f1.z, a1.w + f1.w);
    *(bhalf8*)(wsum + id) = cvt8(s0, s1);
}

// Block (e,j): sorted-slot window [64j, 64j+64) of expert e.
__global__ __launch_bounds__(256) void k_gemm(
    const unsigned short* __restrict__ wsum, const float* __restrict__ x,
    const int* __restrict__ ridx, const float* __restrict__ bias,
    const float* __restrict__ bfv, float* __restrict__ out) {
    __shared__ int pfx[NSB + 1];
    __shared__ int pcs[NSB];
    __shared__ int wc[4];
    __shared__ int stk[TPB];

    int e = blockIdx.x;  // expert-major: expert e pinned to XCD e&7
    int j = blockIdx.y;
    int tid = threadIdx.x;
    int wave = tid >> 6;
    int lane = tid & 63;

    // ---- histogram of expert e per source block, from ridx directly.
    // Thread tid covers tokens [16*tid, 16*tid+16), all inside sb = tid>>4;
    // 16-lane shuffle reduce (verified in round 1). ----
    {
        int c = 0;
        const int4* rp = (const int4*)(ridx + tid * 16);
        #pragma unroll
        for (int i = 0; i < 4; ++i) {
            int4 v = rp[i];
            c += (v.x == e) + (v.y == e) + (v.z == e) + (v.w == e);
        }
        #pragma unroll
        for (int s = 1; s < 16; s <<= 1) c += __shfl_xor(c, s);
        if ((tid & 15) == 0) pcs[tid >> 4] = c;
    }
    __syncthreads();
    if (tid == 0) {
        int a = 0;
        for (int sb = 0; sb < NSB; ++sb) { pfx[sb] = a; a += pcs[sb]; }
        pfx[NSB] = a;
    }
    __syncthreads();

    int cnt = pfx[NSB];
    int start = j * TPB;
    if (start >= cnt) return;  // block-uniform
    int rem = cnt - start;
    int rows = rem < TPB ? rem : TPB;
    int end = start + rows;

    // ---- token-id reconstruction: ballot + prefix rank over the source
    // blocks covering the window (round-0 logic, window width 64). ----
    for (int sb = 0; sb < NSB; ++sb) {
        if (pfx[sb + 1] <= start || pfx[sb] >= end) continue;  // block-uniform
        int tok = sb * 256 + tid;
        bool m = (ridx[tok] == e);
        unsigned long long mask = __ballot(m);
        if (lane == 0) wc[wave] = (int)__popcll(mask);
        __syncthreads();
        int wbase = 0;
        for (int wv = 0; wv < wave; ++wv) wbase += wc[wv];
        int rank = wbase + (int)__popcll(mask & ((1ull << lane) - 1ull));
        int slot = pfx[sb] + rank;
        if (m && slot >= start && slot < end) stk[slot - start] = tok;
        __syncthreads();
    }
    if (tid < TPB && tid >= rows) stk[tid] = stk[0];  // pad with a valid token
    __syncthreads();

    int l15 = lane & 15;
    int quad = lane >> 4;

    // ---- bias hoist: bb[n] for this wave's 64 out-channels. ----
    float bb[4];
    #pragma unroll
    for (int n = 0; n < 4; ++n) {
        int m = wave * 64 + n * 16 + l15;
        bb[n] = bias[e * OUT_F + m] + bfv[m];
    }

    // ---- 64x256 (K=256) tile = 4 token sub-tiles sharing B fragments.
    // Per ks chunk: load 4 B frags once, use for all 4 sub-tiles. ----
    const unsigned short* wrow =
        wsum + e * WEL + (wave * 64 + l15) * IN_F + quad * 8;
    const float* xr[4];
    #pragma unroll
    for (int t = 0; t < 4; ++t)
        xr[t] = x + stk[t * 16 + l15] * IN_F + quad * 8;

    v4f acc[4][4];  // [token-subtile][n]
    #pragma unroll
    for (int t = 0; t < 4; ++t)
        #pragma unroll
        for (int n = 0; n < 4; ++n) acc[t][n] = (v4f){0.f, 0.f, 0.f, 0.f};

    #pragma unroll
    for (int ks = 0; ks < 8; ++ks) {
        bhalf8 b[4];
        #pragma unroll
        for (int n = 0; n < 4; ++n)
            b[n] = *(const bhalf8*)(wrow + n * (16 * IN_F) + ks * 32);
        #pragma unroll
        for (int t = 0; t < 4; ++t) {
            const float4 a0 = *(const float4*)(xr[t] + ks * 32);
            const float4 a1 = *(const float4*)(xr[t] + ks * 32 + 4);
            bhalf8 a = cvt8(a0, a1);
            #pragma unroll
            for (int n = 0; n < 4; ++n)
                acc[t][n] =
                    __builtin_amdgcn_mfma_f32_16x16x32_bf16(a, b[n], acc[t][n], 0, 0, 0);
        }
    }

    // ---- epilogue: scatter rows to out. ----
    #pragma unroll
    for (int t = 0; t < 4; ++t) {
        #pragma unroll
        for (int n = 0; n < 4; ++n) {
            int m = wave * 64 + n * 16 + l15;
            #pragma unroll
            for (int r = 0; r < 4; ++r) {
                int rg = t * 16 + quad * 4 + r;
                if (rg < rows) out[stk[rg] * OUT_F + m] = acc[t][n][r] + bb[n];
            }
        }
    }
}

extern "C" void kernel_launch(void* const* d_in, const int* in_sizes, int n_in,
                              void* d_out, int out_size, void* d_ws, size_t ws_size,
                              hipStream_t stream) {
    (void)in_sizes; (void)n_in; (void)out_size; (void)ws_size;
    const float* x = (const float*)d_in[0];
    const int* ridx = (const int*)d_in[1];
    const float* w = (const float*)d_in[2];
    const float* wf = (const float*)d_in[3];
    const float* bias = (const float*)d_in[4];
    const float* bf = (const float*)d_in[5];
    float* out = (float*)d_out;
    unsigned short* wsum = (unsigned short*)((char*)d_ws + WSUM_OFF);

    k_conv<<<512, 256, 0, stream>>>(w, wf, wsum);
    // capacity 8 tiles * 64 = 512 tokens/expert; counts are Binomial(4096,1/16)
    // (mean 256, sigma 15.5) -> 16.5 sigma margin.
    k_gemm<<<dim3(NEXP, JTILES), 256, 0, stream>>>(wsum, x, ridx, bias, bf, out);
}

// Round 3
// 83.745 us; speedup vs baseline: 1.2112x; 1.0615x over previous
//
#include <hip/hip_runtime.h>

// SwitchLinear: out[b] = x[b] @ (W[route[b]] + Wf)^T + bias[route[b]] + bf
// B=4096, IN=OUT=256, E=16.
//
// 2-dispatch pipeline (verified round-0 structure + B-prefetch):
//  1. k_prep: wsum = bf16(W[e]+Wf) for all experts (512 blocks) +
//     per-source-block expert histograms part[16][16] (16 blocks).
//  2. k_gemm: block (j,e) reconstructs its 16 sorted token ids directly from
//     part[] + ridx via ballot/prefix rank, then does a 16x256 (K=256) bf16
//     MFMA tile. NEW: all 32 B fragments (128 KB wsum slab, L3-resident) are
//     prefetched into registers right after the block-uniform early-exit --
//     they depend only on e, so their latency overlaps the ballot/prefix
//     preamble instead of serializing after it. Bias is hoisted the same way.
//     A-operand is loaded fp32 and converted in-register; bias folded in the
//     epilogue.

#define B_TOK 4096
#define IN_F 256
#define OUT_F 256
#define NEXP 16
#define WEL (OUT_F * IN_F)  // 65536 elems per expert weight
#define NSB 16              // source blocks of 256 tokens each

typedef __attribute__((ext_vector_type(8))) short bhalf8;  // 8 bf16 = 4 VGPRs
typedef __attribute__((ext_vector_type(4))) float v4f;     // MFMA accumulator

// ws layout (bytes)
#define WSUM_OFF 0u         // ushort[1048576]  bf16(W[e]+Wf)
#define PART_OFF 2097152u   // int[16*16]       part[sb][e] histogram

__device__ __forceinline__ unsigned short f2bf(float f) {
    unsigned u = __float_as_uint(f);
    u += 0x7FFFu + ((u >> 16) & 1u);  // round-nearest-even
    return (unsigned short)(u >> 16);
}

// blocks 0..511 : wsum = bf16(W + Wf)   (8 elems/thread)
// blocks 512..527: histogram part[sb][e] (256 tokens/block)
__global__ __launch_bounds__(256) void k_prep(
    const int* __restrict__ ridx, const float* __restrict__ w,
    const float* __restrict__ wf, unsigned short* __restrict__ wsum,
    int* __restrict__ part) {
    int bid = blockIdx.x;
    int tid = threadIdx.x;
    if (bid < 512) {
        int id = (bid * 256 + tid) * 8;
        const float4 a0 = *(const float4*)(w + id);
        const float4 a1 = *(const float4*)(w + id + 4);
        int fo = id & (WEL - 1);
        const float4 f0 = *(const float4*)(wf + fo);
        const float4 f1 = *(const float4*)(wf + fo + 4);
        bhalf8 v;
        v[0] = (short)f2bf(a0.x + f0.x); v[1] = (short)f2bf(a0.y + f0.y);
        v[2] = (short)f2bf(a0.z + f0.z); v[3] = (short)f2bf(a0.w + f0.w);
        v[4] = (short)f2bf(a1.x + f1.x); v[5] = (short)f2bf(a1.y + f1.y);
        v[6] = (short)f2bf(a1.z + f1.z); v[7] = (short)f2bf(a1.w + f1.w);
        *(bhalf8*)(wsum + id) = v;
    } else {
        __shared__ int h[NEXP];
        if (tid < NEXP) h[tid] = 0;
        __syncthreads();
        int sb = bid - 512;
        atomicAdd(&h[ridx[sb * 256 + tid]], 1);
        __syncthreads();
        if (tid < NEXP) part[sb * NEXP + tid] = h[tid];
    }
}

// Block (j,e): sorted-slot window [16j, 16j+16) of expert e.
__global__ __launch_bounds__(256) void k_gemm(
    const unsigned short* __restrict__ wsum, const float* __restrict__ x,
    const int* __restrict__ ridx, const int* __restrict__ part,
    const float* __restrict__ bias, const float* __restrict__ bfv,
    float* __restrict__ out) {
    __shared__ int pfx[NSB + 1];
    __shared__ int wc[4];
    __shared__ int stk[16];

    int e = blockIdx.y;
    int j = blockIdx.x;
    int tid = threadIdx.x;

    __shared__ int pc[NSB];
    if (tid < NSB) pc[tid] = part[tid * NEXP + e];
    __syncthreads();
    if (tid == 0) {
        int a = 0;
        for (int sb = 0; sb < NSB; ++sb) { pfx[sb] = a; a += pc[sb]; }
        pfx[NSB] = a;
    }
    __syncthreads();
    int cnt = pfx[NSB];
    int start = j * 16;
    if (start >= cnt) return;  // block-uniform -> inactive blocks issue no
                               // prefetch traffic
    int rem = cnt - start;
    int rows = rem < 16 ? rem : 16;
    int end = start + rows;

    int wave = tid >> 6;
    int lane = tid & 63;
    int l15 = lane & 15;
    int quad = lane >> 4;

    // ---- B-prefetch: all 32 fragments of this thread's wsum slab. Depends
    // only on e -> issue now, latency overlaps the ballot preamble. ----
    const unsigned short* wbase_p =
        wsum + e * WEL + (wave * 64 + l15) * IN_F + quad * 8;
    bhalf8 bfr[8][4];
    #pragma unroll
    for (int ks = 0; ks < 8; ++ks)
        #pragma unroll
        for (int n = 0; n < 4; ++n)
            bfr[ks][n] = *(const bhalf8*)(wbase_p + n * (16 * IN_F) + ks * 32);

    // ---- bias hoist (independent of stk). ----
    float bb[4];
    #pragma unroll
    for (int n = 0; n < 4; ++n) {
        int m = wave * 64 + n * 16 + l15;
        bb[n] = bias[e * OUT_F + m] + bfv[m];
    }

    // ---- token-id reconstruction: ballot + prefix rank over the 1-2
    // source blocks covering the window (verbatim from verified kernel). ----
    for (int sb = 0; sb < NSB; ++sb) {
        if (pfx[sb + 1] <= start || pfx[sb] >= end) continue;  // block-uniform
        int tok = sb * 256 + tid;
        bool m = (ridx[tok] == e);
        unsigned long long mask = __ballot(m);
        if (lane == 0) wc[wave] = (int)__popcll(mask);
        __syncthreads();
        int wbase = 0;
        for (int wv = 0; wv < wave; ++wv) wbase += wc[wv];
        int rank = wbase + (int)__popcll(mask & ((1ull << lane) - 1ull));
        int slot = pfx[sb] + rank;
        if (m && slot >= start && slot < end) stk[slot - start] = tok;
        __syncthreads();
    }
    if (tid < 16 && tid >= rows) stk[tid] = stk[0];  // pad with a valid token
    __syncthreads();

    // ---- 16x256 (K=256) MFMA tile. A loaded fp32 + converted in-register;
    // B comes from the prefetched registers. ----
    const float* xrow = x + stk[l15] * IN_F + quad * 8;

    v4f acc[4];
    #pragma unroll
    for (int n = 0; n < 4; ++n) acc[n] = (v4f){0.f, 0.f, 0.f, 0.f};

    #pragma unroll
    for (int ks = 0; ks < 8; ++ks) {
        const float4 a0 = *(const float4*)(xrow + ks * 32);
        const float4 a1 = *(const float4*)(xrow + ks * 32 + 4);
        bhalf8 a;
        a[0] = (short)f2bf(a0.x); a[1] = (short)f2bf(a0.y);
        a[2] = (short)f2bf(a0.z); a[3] = (short)f2bf(a0.w);
        a[4] = (short)f2bf(a1.x); a[5] = (short)f2bf(a1.y);
        a[6] = (short)f2bf(a1.z); a[7] = (short)f2bf(a1.w);
        #pragma unroll
        for (int n = 0; n < 4; ++n)
            acc[n] = __builtin_amdgcn_mfma_f32_16x16x32_bf16(a, bfr[ks][n],
                                                             acc[n], 0, 0, 0);
    }

    // ---- epilogue: bias + scatter rows to out (verbatim). ----
    #pragma unroll
    for (int n = 0; n < 4; ++n) {
        int m = wave * 64 + n * 16 + l15;
        #pragma unroll
        for (int r = 0; r < 4; ++r) {
            int row = quad * 4 + r;
            if (row < rows) out[stk[row] * OUT_F + m] = acc[n][r] + bb[n];
        }
    }
}

extern "C" void kernel_launch(void* const* d_in, const int* in_sizes, int n_in,
                              void* d_out, int out_size, void* d_ws, size_t ws_size,
                              hipStream_t stream) {
    (void)in_sizes; (void)n_in; (void)out_size; (void)ws_size;
    const float* x = (const float*)d_in[0];
    const int* ridx = (const int*)d_in[1];
    const float* w = (const float*)d_in[2];
    const float* wf = (const float*)d_in[3];
    const float* bias = (const float*)d_in[4];
    const float* bf = (const float*)d_in[5];
    float* out = (float*)d_out;
    char* ws = (char*)d_ws;

    unsigned short* wsum = (unsigned short*)(ws + WSUM_OFF);
    int* part = (int*)(ws + PART_OFF);

    k_prep<<<528, 256, 0, stream>>>(ridx, w, wf, wsum, part);
    // capacity 32 tiles/expert = 512 tokens; counts are Binomial(4096,1/16)
    // (mean 256, sigma 15.5) -> 16.5 sigma margin.
    k_gemm<<<dim3(32, NEXP), 256, 0, stream>>>(wsum, x, ridx, part, bias, bf, out);
}